// Round 5
// baseline (373.551 us; speedup 1.0000x reference)
//
#include <hip/hip_runtime.h>
#include <hip/hip_bf16.h>

#define S_LEN 2048
#define HID   4096
#define NH    32
#define NKV   8
#define HD    128

typedef __attribute__((ext_vector_type(8))) short short8v;
typedef __attribute__((ext_vector_type(4))) float floatx4;

__device__ __forceinline__ float bf2f(unsigned short u) {
  union { unsigned int u32; float f; } v; v.u32 = ((unsigned int)u) << 16; return v.f;
}
__device__ __forceinline__ unsigned short f2bf(float f) {
  union { float f; unsigned int u; } v; v.f = f;
  unsigned int u = v.u + 0x7fffu + ((v.u >> 16) & 1u);
  return (unsigned short)(u >> 16);
}

__device__ __forceinline__ void gld_lds16(const void* g, void* l) {
  __builtin_amdgcn_global_load_lds((const __attribute__((address_space(1))) void*)g,
                                   (__attribute__((address_space(3))) void*)l, 16, 0, 0);
}

// ---------------- fused f32 -> bf16 convert for all 5 tensors ----------------
__global__ __launch_bounds__(256) void cvt_all(const float* __restrict__ X,  const float* __restrict__ Wq,
                                               const float* __restrict__ Wk, const float* __restrict__ Wv,
                                               const float* __restrict__ Wo,
                                               unsigned short* __restrict__ Xb,  unsigned short* __restrict__ Wqb,
                                               unsigned short* __restrict__ Wkb, unsigned short* __restrict__ Wvb,
                                               unsigned short* __restrict__ Wob) {
  const int c0 = 2097152;            // X
  const int c1 = c0 + 4194304;       // Wq
  const int c2 = c1 + 1048576;       // Wk
  const int c3 = c2 + 1048576;       // Wv
  const int c4 = c3 + 4194304;       // Wo
  int i = blockIdx.x * blockDim.x + threadIdx.x;
  int stride = gridDim.x * blockDim.x;
  for (; i < c4; i += stride) {
    const float* src; unsigned short* dst; int off;
    if (i < c0)      { src = X;  dst = Xb;  off = i; }
    else if (i < c1) { src = Wq; dst = Wqb; off = i - c0; }
    else if (i < c2) { src = Wk; dst = Wkb; off = i - c1; }
    else if (i < c3) { src = Wv; dst = Wvb; off = i - c2; }
    else             { src = Wo; dst = Wob; off = i - c3; }
    float4 v = ((const float4*)src)[off];
    ushort4 o;
    o.x = f2bf(v.x); o.y = f2bf(v.y); o.z = f2bf(v.z); o.w = f2bf(v.w);
    ((ushort4*)dst)[off] = o;
  }
}

// ---------------- Pipelined GEMM core: C[m,n] = sum_k A[m,k]*B[n,k], K=4096.
// Tile 256(M) x 128(N), BK=32, 512 thr = 8 waves (4M x 2N), per-wave 64x64.
// 3 LDS buffers; depth-2 prefetch with counted vmcnt(3).
__device__ __forceinline__ void gemm_pipe_core(const unsigned short* __restrict__ A,
                                               const unsigned short* __restrict__ B,
                                               unsigned short* lds,
                                               int brow, int bcol, int tid,
                                               floatx4 acc[4][4]) {
  const int K = 4096;
  const int w = tid >> 6, lane = tid & 63;
  const int fr = lane & 15, fq = lane >> 4;
  const int wm = w >> 1, wn = w & 1;

  const int rA0 = tid >> 2, sA = tid & 3;
  const unsigned short* pA0 = A + (size_t)(brow + rA0) * K       + ((sA ^ (rA0 & 3)) << 3);
  const unsigned short* pA1 = A + (size_t)(brow + 128 + rA0) * K + ((sA ^ (rA0 & 3)) << 3);
  const unsigned short* pB0 = B + (size_t)(bcol + rA0) * K       + ((sA ^ (rA0 & 3)) << 3);

  const int sl = (fq ^ (fr & 3)) << 3;
  int aoff[4], boff[4];
#pragma unroll
  for (int m = 0; m < 4; ++m) aoff[m] = (wm * 64 + m * 16 + fr) * 32 + sl;
#pragma unroll
  for (int n = 0; n < 4; ++n) boff[n] = 8192 + (wn * 64 + n * 16 + fr) * 32 + sl;

#define STAGEG(buf, kofs)                                        \
  do {                                                           \
    unsigned short* b_ = lds + (buf) * 12288 + w * 512;          \
    gld_lds16(pA0 + (kofs), b_);                                 \
    gld_lds16(pA1 + (kofs), b_ + 4096);                          \
    gld_lds16(pB0 + (kofs), b_ + 8192);                          \
  } while (0)

  STAGEG(0, 0);
  STAGEG(1, 32);
  asm volatile("s_waitcnt vmcnt(3)" ::: "memory");
  __syncthreads();

  int cb = 0, nb = 2;
  for (int t = 0; t < 128; ++t) {
    if (t + 2 < 128) STAGEG(nb, (t + 2) * 32);

    const unsigned short* Lc = lds + cb * 12288;
    short8v a[4], b[4];
#pragma unroll
    for (int m = 0; m < 4; ++m) a[m] = *(const short8v*)&Lc[aoff[m]];
#pragma unroll
    for (int n = 0; n < 4; ++n) b[n] = *(const short8v*)&Lc[boff[n]];

    __builtin_amdgcn_s_setprio(1);
#pragma unroll
    for (int m = 0; m < 4; ++m)
#pragma unroll
      for (int n = 0; n < 4; ++n)
        acc[m][n] = __builtin_amdgcn_mfma_f32_16x16x32_bf16(a[m], b[n], acc[m][n], 0, 0, 0);
    __builtin_amdgcn_s_setprio(0);

    if (t + 1 < 128) {
      if (t + 2 < 128) asm volatile("s_waitcnt vmcnt(3)" ::: "memory");
      else             asm volatile("s_waitcnt vmcnt(0)" ::: "memory");
      __syncthreads();
      cb = (cb == 2) ? 0 : cb + 1;
      nb = (nb == 2) ? 0 : nb + 1;
    }
  }
#undef STAGEG
}

// Fused QKV projection. Grid (48, 8): bx<32 Q, 32..39 K, 40..47 V(transposed out).
__global__ __launch_bounds__(512, 4) void gemm_qkv(const unsigned short* __restrict__ Xb,
                                                   const unsigned short* __restrict__ Wqb,
                                                   const unsigned short* __restrict__ Wkb,
                                                   const unsigned short* __restrict__ Wvb,
                                                   unsigned short* __restrict__ Qg,
                                                   unsigned short* __restrict__ Kg,
                                                   unsigned short* __restrict__ Vt) {
  __shared__ unsigned short lds[3 * 12288];
  const int bx = blockIdx.x;
  const unsigned short* B; unsigned short* C; int mode, bcol, ldc;
  if (bx < 32)      { B = Wqb; C = Qg; mode = 0; bcol = bx * 128;        ldc = HID;  }
  else if (bx < 40) { B = Wkb; C = Kg; mode = 0; bcol = (bx - 32) * 128; ldc = 1024; }
  else              { B = Wvb; C = Vt; mode = 1; bcol = (bx - 40) * 128; ldc = 0;    }
  const int brow = blockIdx.y * 256;
  const int tid = threadIdx.x;
  floatx4 acc[4][4] = {};
  gemm_pipe_core(Xb, B, lds, brow, bcol, tid, acc);

  const int w = tid >> 6, lane = tid & 63;
  const int fr = lane & 15, fq = lane >> 4;
  const int r0 = brow + (w >> 1) * 64 + fq * 4;
  const int c0 = bcol + (w & 1) * 64 + fr;
  if (mode == 0) {
#pragma unroll
    for (int m = 0; m < 4; ++m)
#pragma unroll
      for (int n = 0; n < 4; ++n)
#pragma unroll
        for (int r = 0; r < 4; ++r)
          C[(size_t)(r0 + m * 16 + r) * ldc + c0 + n * 16] = f2bf(acc[m][n][r]);
  } else {
#pragma unroll
    for (int m = 0; m < 4; ++m)
#pragma unroll
      for (int n = 0; n < 4; ++n) {
        ushort4 pk;
        pk.x = f2bf(acc[m][n][0]); pk.y = f2bf(acc[m][n][1]);
        pk.z = f2bf(acc[m][n][2]); pk.w = f2bf(acc[m][n][3]);
        *(ushort4*)&C[(size_t)(c0 + n * 16) * S_LEN + (r0 + m * 16)] = pk;
      }
  }
}

// Output projection: f32 C to d_out. Grid (32, 8).
__global__ __launch_bounds__(512, 4) void gemm_o(const unsigned short* __restrict__ Ao,
                                                 const unsigned short* __restrict__ Wob,
                                                 float* __restrict__ Out) {
  __shared__ unsigned short lds[3 * 12288];
  const int tid = threadIdx.x;
  const int brow = blockIdx.y * 256, bcol = blockIdx.x * 128;
  floatx4 acc[4][4] = {};
  gemm_pipe_core(Ao, Wob, lds, brow, bcol, tid, acc);
  const int w = tid >> 6, lane = tid & 63;
  const int fr = lane & 15, fq = lane >> 4;
  const int r0 = brow + (w >> 1) * 64 + fq * 4;
  const int c0 = bcol + (w & 1) * 64 + fr;
#pragma unroll
  for (int m = 0; m < 4; ++m)
#pragma unroll
    for (int n = 0; n < 4; ++n)
#pragma unroll
      for (int r = 0; r < 4; ++r)
        Out[(size_t)(r0 + m * 16 + r) * HID + c0 + n * 16] = acc[m][n][r];
}

// ---------------- RoPE + per-head relayout ----------------
// Q additionally scaled by log2(e)/sqrt(128) so attention softmax can use exp2.
__global__ __launch_bounds__(256) void rope_kernel(const unsigned short* __restrict__ In,
                                                   const float* __restrict__ cosT,
                                                   const float* __restrict__ sinT,
                                                   unsigned short* __restrict__ Out,
                                                   int nh, float scale) {
  int idx = blockIdx.x * 256 + threadIdx.x;
  int j = idx & 63;
  int s = (idx >> 6) & (S_LEN - 1);
  int h = idx >> 17;
  unsigned int pr = *(const unsigned int*)(In + (size_t)s * (nh * HD) + h * HD + 2 * j);
  float q1 = bf2f((unsigned short)(pr & 0xffffu));
  float q2 = bf2f((unsigned short)(pr >> 16));
  float c = cosT[s * 64 + j], sn = sinT[s * 64 + j];
  unsigned short* op = Out + ((size_t)h * S_LEN + s) * HD + j;
  op[0]  = f2bf(scale * (q1 * c - q2 * sn));
  op[64] = f2bf(scale * (q2 * c + q1 * sn));
}

// ---------------- Flash attention: paired q-tiles, operand-shared MFMA ----------------
// Block (h, p) handles q-tiles {31-p, p}: exactly 33 tile-works per block.
// Grid 512 = 2 blocks/CU exactly (80 KB LDS each). Loop1 (t<=p): both tiles
// share bk/bv LDS reads; loop2: hi only. Softmax in exp2 domain, defer-max.
__device__ __forceinline__ void softmax_tile(floatx4 s[4], float m[4], float l[4],
                                             floatx4 o[8], unsigned short* pw,
                                             int fr, int fq) {
  float vmax[4];
#pragma unroll
  for (int r = 0; r < 4; ++r)
    vmax[r] = fmaxf(fmaxf(s[0][r], s[1][r]), fmaxf(s[2][r], s[3][r]));
#pragma unroll
  for (int off = 8; off; off >>= 1)
#pragma unroll
    for (int r = 0; r < 4; ++r)
      vmax[r] = fmaxf(vmax[r], __shfl_xor(vmax[r], off));
  float d = fmaxf(fmaxf(vmax[0] - m[0], vmax[1] - m[1]),
                  fmaxf(vmax[2] - m[2], vmax[3] - m[3]));
  if (!__all(d <= 8.0f)) {          // defer-max: skip rescale when growth small
#pragma unroll
    for (int r = 0; r < 4; ++r) {
      float mn = fmaxf(m[r], vmax[r]);
      float al = exp2f(m[r] - mn);
      m[r] = mn;
      l[r] *= al;
#pragma unroll
      for (int nf = 0; nf < 8; ++nf) o[nf][r] *= al;
    }
  }
  float psum[4] = {0.f, 0.f, 0.f, 0.f};
#pragma unroll
  for (int n = 0; n < 4; ++n)
#pragma unroll
    for (int r = 0; r < 4; ++r) {
      float pf = exp2f(s[n][r] - m[r]);
      psum[r] += pf;
      int q = fq * 4 + r;
      int g = ((n * 2) + (fr >> 3)) ^ (q & 7);          // swizzled 8-elem slot
      pw[q * 64 + g * 8 + (fr & 7)] = f2bf(pf);
    }
#pragma unroll
  for (int r = 0; r < 4; ++r) l[r] += psum[r];
}

__global__ __launch_bounds__(256) void attn_fwd(const unsigned short* __restrict__ Qr,
                                                const unsigned short* __restrict__ Kr,
                                                const unsigned short* __restrict__ Vt,
                                                unsigned short* __restrict__ Ao) {
  __shared__ unsigned short Kl[2][64 * 128];   // [kv][128] swizzled (cb ^ (row&7)<<4)
  __shared__ unsigned short Vl[2][64 * 128];   // [d][kv] swizzled
  __shared__ unsigned short Pl[2][4][16 * 64]; // [tileSel][wave][q][kv] slot-swizzled
  const int id = blockIdx.x;
  const int swz = (id & 7) * 64 + (id >> 3);    // XCD c <-> kv-head c (512 = 8*64)
  const int h = swz >> 4, p = swz & 15;
  const int hk = h >> 2;
  const int qtH = 31 - p;
  const int qbH = qtH * 64, qbL = p * 64;
  const int tid = threadIdx.x, w = tid >> 6, lane = tid & 63;
  const int fr = lane & 15, fq = lane >> 4;

  short8v aqH[4], aqL[4];
  {
    const unsigned short* qh = Qr + ((size_t)(h * S_LEN + qbH + w * 16 + fr)) * HD + fq * 8;
    const unsigned short* ql = Qr + ((size_t)(h * S_LEN + qbL + w * 16 + fr)) * HD + fq * 8;
#pragma unroll
    for (int ks = 0; ks < 4; ++ks) {
      aqH[ks] = *(const short8v*)(qh + ks * 32);
      aqL[ks] = *(const short8v*)(ql + ks * 32);
    }
  }

  const int kcb = ((tid & 15) * 16) ^ (((tid >> 4) & 7) << 4);
  const unsigned short* pK0 = Kr + ((size_t)hk * S_LEN + (tid >> 4)) * HD + (kcb >> 1);
  const int vcb = ((tid & 7) * 16) ^ (((tid >> 3) & 7) << 4);
  const unsigned short* pV0 = Vt + ((size_t)hk * HD + (tid >> 3)) * S_LEN + (vcb >> 1);

  float mH[4], lH[4], mL[4], lL[4];
#pragma unroll
  for (int r = 0; r < 4; ++r) { mH[r] = -1e30f; lH[r] = 0.f; mL[r] = -1e30f; lL[r] = 0.f; }
  floatx4 oH[8] = {}, oL[8] = {};

#define STAGE(buf, t)                                                          \
  do {                                                                         \
    const unsigned short* pk_ = pK0 + (size_t)(t) * 64 * HD;                   \
    const unsigned short* pv_ = pV0 + (t) * 64;                                \
    _Pragma("unroll")                                                          \
    for (int j = 0; j < 4; ++j)                                                \
      gld_lds16(pk_ + (size_t)j * 16 * HD, &Kl[buf][w * 512 + j * 2048]);      \
    _Pragma("unroll")                                                          \
    for (int j = 0; j < 4; ++j)                                                \
      gld_lds16(pv_ + (size_t)j * 32 * S_LEN, &Vl[buf][w * 512 + j * 2048]);   \
  } while (0)

  STAGE(0, 0);
  asm volatile("s_waitcnt vmcnt(0)" ::: "memory");
  __syncthreads();

  int cur = 0;
  // -------- loop1: t = 0..p — both q-tiles, shared bk/bv reads --------
  for (int t = 0; t <= p; ++t) {
    STAGE(cur ^ 1, t + 1);   // t+1 <= p+1 <= 16 <= qtH: always valid
    const unsigned short* Kc = &Kl[cur][0];
    const unsigned short* Vc = &Vl[cur][0];

    floatx4 sH[4] = {}, sL[4] = {};
    __builtin_amdgcn_s_setprio(1);
#pragma unroll
    for (int ks = 0; ks < 4; ++ks) {
      short8v bk[4];
#pragma unroll
      for (int n = 0; n < 4; ++n) {
        int row = n * 16 + fr;
        int cb = (ks * 64 + fq * 16) ^ ((row & 7) << 4);
        bk[n] = *(const short8v*)&Kc[row * 128 + (cb >> 1)];
      }
#pragma unroll
      for (int n = 0; n < 4; ++n) {
        sH[n] = __builtin_amdgcn_mfma_f32_16x16x32_bf16(aqH[ks], bk[n], sH[n], 0, 0, 0);
        sL[n] = __builtin_amdgcn_mfma_f32_16x16x32_bf16(aqL[ks], bk[n], sL[n], 0, 0, 0);
      }
    }
    __builtin_amdgcn_s_setprio(0);

    if (t == p) {  // diagonal of LO tile
#pragma unroll
      for (int n = 0; n < 4; ++n) {
        int col = t * 64 + n * 16 + fr;
#pragma unroll
        for (int r = 0; r < 4; ++r)
          if (col > qbL + w * 16 + fq * 4 + r) sL[n][r] = -1e30f;
      }
    }

    softmax_tile(sH, mH, lH, oH, &Pl[0][w][0], fr, fq);
    softmax_tile(sL, mL, lL, oL, &Pl[1][w][0], fr, fq);

    short8v paH[2], paL[2];
#pragma unroll
    for (int ks = 0; ks < 2; ++ks) {
      int g = (ks * 4 + fq) ^ (fr & 7);
      paH[ks] = *(const short8v*)&Pl[0][w][fr * 64 + g * 8];
      paL[ks] = *(const short8v*)&Pl[1][w][fr * 64 + g * 8];
    }
    __builtin_amdgcn_s_setprio(1);
#pragma unroll
    for (int nf = 0; nf < 8; ++nf) {
#pragma unroll
      for (int ks = 0; ks < 2; ++ks) {
        int row = nf * 16 + fr;
        int cb = (ks * 64 + fq * 16) ^ ((row & 7) << 4);
        short8v bv = *(const short8v*)&Vc[row * 64 + (cb >> 1)];
        oH[nf] = __builtin_amdgcn_mfma_f32_16x16x32_bf16(paH[ks], bv, oH[nf], 0, 0, 0);
        oL[nf] = __builtin_amdgcn_mfma_f32_16x16x32_bf16(paL[ks], bv, oL[nf], 0, 0, 0);
      }
    }
    __builtin_amdgcn_s_setprio(0);

    asm volatile("s_waitcnt vmcnt(0)" ::: "memory");
    __syncthreads();
    cur ^= 1;
  }

  // -------- loop2: t = p+1..qtH — hi tile only --------
  for (int t = p + 1; t <= qtH; ++t) {
    if (t < qtH) STAGE(cur ^ 1, t + 1);
    const unsigned short* Kc = &Kl[cur][0];
    const unsigned short* Vc = &Vl[cur][0];

    floatx4 sH[4] = {};
    __builtin_amdgcn_s_setprio(1);
#pragma unroll
    for (int ks = 0; ks < 4; ++ks) {
      short8v bk[4];
#pragma unroll
      for (int n = 0; n < 4; ++n) {
        int row = n * 16 + fr;
        int cb = (ks * 64 + fq * 16) ^ ((row & 7) << 4);
        bk[n] = *(const short8v*)&Kc[row * 128 + (cb >> 1)];
      }
#pragma unroll
      for (int n = 0; n < 4; ++n)
        sH[n] = __builtin_amdgcn_mfma_f32_16x16x32_bf16(aqH[ks], bk[n], sH[n], 0, 0, 0);
    }
    __builtin_amdgcn_s_setprio(0);

    if (t == qtH) {  // diagonal of HI tile
#pragma unroll
      for (int n = 0; n < 4; ++n) {
        int col = t * 64 + n * 16 + fr;
#pragma unroll
        for (int r = 0; r < 4; ++r)
          if (col > qbH + w * 16 + fq * 4 + r) sH[n][r] = -1e30f;
      }
    }

    softmax_tile(sH, mH, lH, oH, &Pl[0][w][0], fr, fq);

    short8v paH[2];
#pragma unroll
    for (int ks = 0; ks < 2; ++ks) {
      int g = (ks * 4 + fq) ^ (fr & 7);
      paH[ks] = *(const short8v*)&Pl[0][w][fr * 64 + g * 8];
    }
    __builtin_amdgcn_s_setprio(1);
#pragma unroll
    for (int nf = 0; nf < 8; ++nf) {
#pragma unroll
      for (int ks = 0; ks < 2; ++ks) {
        int row = nf * 16 + fr;
        int cb = (ks * 64 + fq * 16) ^ ((row & 7) << 4);
        short8v bv = *(const short8v*)&Vc[row * 64 + (cb >> 1)];
        oH[nf] = __builtin_amdgcn_mfma_f32_16x16x32_bf16(paH[ks], bv, oH[nf], 0, 0, 0);
      }
    }
    __builtin_amdgcn_s_setprio(0);

    if (t < qtH) {
      asm volatile("s_waitcnt vmcnt(0)" ::: "memory");
      __syncthreads();
      cur ^= 1;
    }
  }
#undef STAGE

  // -------- epilogue: normalize + write both q-tiles --------
  float sumH[4], sumL[4];
#pragma unroll
  for (int r = 0; r < 4; ++r) { sumH[r] = lH[r]; sumL[r] = lL[r]; }
#pragma unroll
  for (int off = 8; off; off >>= 1)
#pragma unroll
    for (int r = 0; r < 4; ++r) {
      sumH[r] += __shfl_xor(sumH[r], off);
      sumL[r] += __shfl_xor(sumL[r], off);
    }

  unsigned short* aoH = Ao + (size_t)(qbH + w * 16 + fq * 4) * HID + h * HD + fr;
  unsigned short* aoL = Ao + (size_t)(qbL + w * 16 + fq * 4) * HID + h * HD + fr;
#pragma unroll
  for (int r = 0; r < 4; ++r) {
    float rH = 1.0f / sumH[r], rL = 1.0f / sumL[r];
#pragma unroll
    for (int nf = 0; nf < 8; ++nf) {
      aoH[(size_t)r * HID + nf * 16] = f2bf(oH[nf][r] * rH);
      aoL[(size_t)r * HID + nf * 16] = f2bf(oL[nf][r] * rL);
    }
  }
}

// ---------------- launch ----------------
extern "C" void kernel_launch(void* const* d_in, const int* in_sizes, int n_in,
                              void* d_out, int out_size, void* d_ws, size_t ws_size,
                              hipStream_t stream) {
  (void)in_sizes; (void)n_in; (void)out_size; (void)ws_size;
  const float* X    = (const float*)d_in[0];
  const float* cosT = (const float*)d_in[3];
  const float* sinT = (const float*)d_in[4];
  const float* Wq   = (const float*)d_in[5];
  const float* Wk   = (const float*)d_in[6];
  const float* Wv   = (const float*)d_in[7];
  const float* Wo   = (const float*)d_in[8];

  char* ws = (char*)d_ws;
  size_t off = 0;
  auto alloc = [&](size_t bytes) { char* p = ws + off; off += (bytes + 255) & ~(size_t)255; return p; };
  unsigned short* Xb  = (unsigned short*)alloc((size_t)S_LEN * HID * 2);
  unsigned short* Wqb = (unsigned short*)alloc((size_t)HID * HID * 2);
  unsigned short* Wkb = (unsigned short*)alloc((size_t)1024 * HID * 2);
  unsigned short* Wvb = (unsigned short*)alloc((size_t)1024 * HID * 2);
  unsigned short* Wob = (unsigned short*)alloc((size_t)HID * HID * 2);
  unsigned short* Qg  = (unsigned short*)alloc((size_t)S_LEN * HID * 2);
  unsigned short* Kg  = (unsigned short*)alloc((size_t)S_LEN * 1024 * 2);
  unsigned short* Vt  = (unsigned short*)alloc((size_t)1024 * S_LEN * 2);
  unsigned short* Qr = Wqb;                              // aliases, stream-ordered lifetimes
  unsigned short* Kr = Wqb + (size_t)NH * S_LEN * HD;
  unsigned short* Ao = Xb;

  cvt_all<<<2048, 256, 0, stream>>>(X, Wq, Wk, Wv, Wo, Xb, Wqb, Wkb, Wvb, Wob);
  gemm_qkv<<<dim3(48, 8), 512, 0, stream>>>(Xb, Wqb, Wkb, Wvb, Qg, Kg, Vt);
  // Q scale = log2(e)/sqrt(128) so attention uses exp2 directly
  rope_kernel<<<(NH * S_LEN * 64) / 256, 256, 0, stream>>>(Qg, cosT, sinT, Qr, NH, 0.12751744f);
  rope_kernel<<<(NKV * S_LEN * 64) / 256, 256, 0, stream>>>(Kg, cosT, sinT, Kr, NKV, 1.0f);
  attn_fwd<<<512, 256, 0, stream>>>(Qr, Kr, Vt, Ao);
  gemm_o<<<dim3(32, 8), 512, 0, stream>>>(Ao, Wob, (float*)d_out);
}